// Round 1
// baseline (869.304 us; speedup 1.0000x reference)
//
#include <hip/hip_runtime.h>

#define NN   3072
#define DIMF 3
#define MK   3
#define EE   98304
#define CUMC 36
#define HIDC 64
#define OUTC 5

// R row length in floats: N*9 = 27648 = 27 * 1024 (so 1024-float block tiles
// never straddle an i-row, and each thread's float4 never straddles one either).
#define ROWF 27648u

__device__ __forceinline__ float tanh_fast(float x) {
    // tanh(x) = 1 - 2/(exp(2x)+1); safe at +/-inf (no inf/inf).
    float t = __expf(2.0f * x);
    return 1.0f - 2.0f * __builtin_amdgcn_rcpf(t + 1.0f);
}

// ---- A = x @ Ws[0:3], B = x @ Ws[3:6]  (both [N,9]) ----
__global__ void ab_kernel(const float* __restrict__ x, const float* __restrict__ Ws,
                          float* __restrict__ Aa, float* __restrict__ Bb) {
    int id = blockIdx.x * 256 + threadIdx.x;
    if (id >= NN * 9) return;
    int n = id / 9;
    int c = id - n * 9;
    float x0 = x[n * 3 + 0], x1 = x[n * 3 + 1], x2 = x[n * 3 + 2];
    Aa[id] = x0 * Ws[0 * 9 + c] + x1 * Ws[1 * 9 + c] + x2 * Ws[2 * 9 + c];
    Bb[id] = x0 * Ws[3 * 9 + c] + x1 * Ws[4 * 9 + c] + x2 * Ws[5 * 9 + c];
}

// ---- R[i,j,c] = tanh(A[i,c] + B[j,c] + bs[c]), one float4 per thread ----
__global__ __launch_bounds__(256) void r_kernel(const float* __restrict__ Aa,
                                                const float* __restrict__ Bb,
                                                const float* __restrict__ bs,
                                                float* __restrict__ R) {
    unsigned v = blockIdx.x * 256u + threadIdx.x;   // float4 index
    unsigned off = v * 4u;
    unsigned i = off / ROWF;                        // block-uniform
    unsigned r = off - i * ROWF;
    unsigned j = r / 9u;
    unsigned c = r - j * 9u;
    float po[4];
#pragma unroll
    for (int u = 0; u < 4; ++u) {
        po[u] = tanh_fast(Aa[i * 9u + c] + Bb[j * 9u + c] + bs[c]);
        ++c;
        if (c == 9u) { c = 0u; ++j; }
    }
    reinterpret_cast<float4*>(R)[v] = make_float4(po[0], po[1], po[2], po[3]);
}

// ---- hop 1: h1[t, k*3+d] += K[k,e] * x[s,d]; deg[t] += 1 ----
__global__ void edge1_kernel(const int* __restrict__ src, const int* __restrict__ tgt,
                             const float* __restrict__ K, const float* __restrict__ x,
                             float* __restrict__ h1, float* __restrict__ deg) {
    int e = blockIdx.x * 256 + threadIdx.x;
    if (e >= EE) return;
    int s = src[e], t = tgt[e];
    float x0 = x[s * 3 + 0], x1 = x[s * 3 + 1], x2 = x[s * 3 + 2];
#pragma unroll
    for (int k = 0; k < MK; ++k) {
        float kv = K[k * EE + e];
        atomicAdd(&h1[t * 9 + k * 3 + 0], kv * x0);
        atomicAdd(&h1[t * 9 + k * 3 + 1], kv * x1);
        atomicAdd(&h1[t * 9 + k * 3 + 2], kv * x2);
    }
    atomicAdd(&deg[t], 1.0f);
}

// ---- hop 2: h2[t, k*9+d] += K[k,e] * h1[s,d] ----
__global__ void edge2_kernel(const int* __restrict__ src, const int* __restrict__ tgt,
                             const float* __restrict__ K, const float* __restrict__ h1,
                             float* __restrict__ h2) {
    int e = blockIdx.x * 256 + threadIdx.x;
    if (e >= EE) return;
    int s = src[e], t = tgt[e];
    float m[9];
#pragma unroll
    for (int d = 0; d < 9; ++d) m[d] = h1[s * 9 + d];
#pragma unroll
    for (int k = 0; k < MK; ++k) {
        float kv = K[k * EE + e];
#pragma unroll
        for (int d = 0; d < 9; ++d)
            atomicAdd(&h2[t * 27 + k * 9 + d], kv * m[d]);
    }
}

// ---- mean-agg numerator: agg[t, :] += [h1|h2][s, :] ----
__global__ void edge3_kernel(const int* __restrict__ src, const int* __restrict__ tgt,
                             const float* __restrict__ h1, const float* __restrict__ h2,
                             float* __restrict__ agg) {
    int e = blockIdx.x * 256 + threadIdx.x;
    if (e >= EE) return;
    int s = src[e], t = tgt[e];
#pragma unroll
    for (int c = 0; c < 9; ++c)
        atomicAdd(&agg[t * CUMC + c], h1[s * 9 + c]);
#pragma unroll
    for (int c = 0; c < 27; ++c)
        atomicAdd(&agg[t * CUMC + 9 + c], h2[s * 27 + c]);
}

// ---- x36 = relu((agg/deg) @ W_conv + b_conv) ----
__global__ void conv_kernel(const float* __restrict__ agg, const float* __restrict__ deg,
                            const float* __restrict__ Wc, const float* __restrict__ bc,
                            float* __restrict__ x36) {
    int id = blockIdx.x * 256 + threadIdx.x;
    if (id >= NN * CUMC) return;
    int n = id / CUMC;
    int c = id - n * CUMC;
    float dv = deg[n];
    if (dv < 1.0f) dv = 1.0f;
    float inv = 1.0f / dv;
    float acc = 0.0f;
#pragma unroll 4
    for (int k = 0; k < CUMC; ++k)
        acc += agg[n * CUMC + k] * Wc[k * CUMC + c];
    acc = acc * inv + bc[c];
    x36[id] = acc > 0.0f ? acc : 0.0f;
}

// ---- h64 = relu(x36 @ W1 + b1) ----
__global__ void mlp1_kernel(const float* __restrict__ x36, const float* __restrict__ W1,
                            const float* __restrict__ b1, float* __restrict__ h64) {
    int id = blockIdx.x * 256 + threadIdx.x;
    if (id >= NN * HIDC) return;
    int n = id >> 6;
    int c = id & 63;
    float acc = b1[c];
#pragma unroll 4
    for (int k = 0; k < CUMC; ++k)
        acc += x36[n * CUMC + k] * W1[k * HIDC + c];
    h64[id] = acc > 0.0f ? acc : 0.0f;
}

// ---- out = h64 @ W2 + b2 ----
__global__ void mlp2_kernel(const float* __restrict__ h64, const float* __restrict__ W2,
                            const float* __restrict__ b2, float* __restrict__ out) {
    int id = blockIdx.x * 256 + threadIdx.x;
    if (id >= NN * OUTC) return;
    int n = id / OUTC;
    int c = id - n * OUTC;
    float acc = b2[c];
#pragma unroll 8
    for (int k = 0; k < HIDC; ++k)
        acc += h64[n * HIDC + k] * W2[k * OUTC + c];
    out[id] = acc;
}

extern "C" void kernel_launch(void* const* d_in, const int* in_sizes, int n_in,
                              void* d_out, int out_size, void* d_ws, size_t ws_size,
                              hipStream_t stream) {
    const float* x   = (const float*)d_in[0];
    const int*   ei  = (const int*)  d_in[1];
    const float* Kv  = (const float*)d_in[2];
    const float* Ws  = (const float*)d_in[3];
    const float* bsh = (const float*)d_in[4];
    const float* Wc  = (const float*)d_in[5];
    const float* bc  = (const float*)d_in[6];
    const float* W1  = (const float*)d_in[7];
    const float* b1  = (const float*)d_in[8];
    const float* W2  = (const float*)d_in[9];
    const float* b2  = (const float*)d_in[10];

    const int* src = ei;
    const int* tgt = ei + EE;

    float* out  = (float*)d_out;                 // [N,5]
    float* Rout = out + NN * OUTC;               // [N,N,9], 16B-aligned (15360*4 % 16 == 0)

    float* ws  = (float*)d_ws;
    float* h1  = ws;                              // N*9
    float* h2  = h1 + NN * 9;                     // N*27
    float* deg = h2 + NN * 27;                    // N
    float* agg = deg + NN;                        // N*36
    float* Aa  = agg + NN * CUMC;                 // N*9
    float* Bb  = Aa + NN * 9;                     // N*9
    float* x36 = Bb + NN * 9;                     // N*36
    float* h64 = x36 + NN * CUMC;                 // N*64

    // Zero the atomic-accumulated region (h1,h2,deg,agg are contiguous).
    size_t zero_bytes = (size_t)(NN * 9 + NN * 27 + NN + NN * CUMC) * sizeof(float);
    hipMemsetAsync(ws, 0, zero_bytes, stream);

    ab_kernel<<<(NN * 9 + 255) / 256, 256, 0, stream>>>(x, Ws, Aa, Bb);

    // Big write-bound kernel: 84,934,656 floats / 4 per thread / 256 per block.
    unsigned r_blocks = (unsigned)(((size_t)NN * NN * 9 / 4 + 255) / 256);  // 82944
    r_kernel<<<r_blocks, 256, 0, stream>>>(Aa, Bb, bsh, Rout);

    edge1_kernel<<<EE / 256, 256, 0, stream>>>(src, tgt, Kv, x, h1, deg);
    edge2_kernel<<<EE / 256, 256, 0, stream>>>(src, tgt, Kv, h1, h2);
    edge3_kernel<<<EE / 256, 256, 0, stream>>>(src, tgt, h1, h2, agg);

    conv_kernel<<<(NN * CUMC + 255) / 256, 256, 0, stream>>>(agg, deg, Wc, bc, x36);
    mlp1_kernel<<<(NN * HIDC + 255) / 256, 256, 0, stream>>>(x36, W1, b1, h64);
    mlp2_kernel<<<(NN * OUTC + 255) / 256, 256, 0, stream>>>(h64, W2, b2, out);
}

// Round 2
// 541.333 us; speedup vs baseline: 1.6059x; 1.6059x over previous
//
#include <hip/hip_runtime.h>

#define NN   3072
#define DIMF 3
#define MK   3
#define EE   98304
#define CUMC 36
#define HIDC 64
#define OUTC 5

// R row length in floats: N*9 = 27648 = 27 * 1024 (1024-float block tiles and
// per-thread float4s never straddle an i-row).
#define ROWF 27648u

__device__ __forceinline__ float tanh_fast(float x) {
    // tanh(x) = 1 - 2/(exp(2x)+1); safe at +/-inf (no inf/inf).
    float t = __expf(2.0f * x);
    return 1.0f - 2.0f * __builtin_amdgcn_rcpf(t + 1.0f);
}

// ---- A = x @ Ws[0:3], B = x @ Ws[3:6]  (both [N,9]) ----
__global__ void ab_kernel(const float* __restrict__ x, const float* __restrict__ Ws,
                          float* __restrict__ Aa, float* __restrict__ Bb) {
    int id = blockIdx.x * 256 + threadIdx.x;
    if (id >= NN * 9) return;
    int n = id / 9;
    int c = id - n * 9;
    float x0 = x[n * 3 + 0], x1 = x[n * 3 + 1], x2 = x[n * 3 + 2];
    Aa[id] = x0 * Ws[0 * 9 + c] + x1 * Ws[1 * 9 + c] + x2 * Ws[2 * 9 + c];
    Bb[id] = x0 * Ws[3 * 9 + c] + x1 * Ws[4 * 9 + c] + x2 * Ws[5 * 9 + c];
}

// ---- R[i,j,c] = tanh(A[i,c] + B[j,c] + bs[c]), one float4 per thread ----
// Write-roofline kernel: 340 MB of coalesced float4 stores.
__global__ __launch_bounds__(256) void r_kernel(const float* __restrict__ Aa,
                                                const float* __restrict__ Bb,
                                                const float* __restrict__ bs,
                                                float* __restrict__ R) {
    unsigned v = blockIdx.x * 256u + threadIdx.x;   // float4 index
    unsigned off = v * 4u;
    unsigned i = off / ROWF;                        // block-uniform
    unsigned r = off - i * ROWF;
    unsigned j = r / 9u;
    unsigned c = r - j * 9u;
    float po[4];
#pragma unroll
    for (int u = 0; u < 4; ++u) {
        po[u] = tanh_fast(Aa[i * 9u + c] + Bb[j * 9u + c] + bs[c]);
        ++c;
        if (c == 9u) { c = 0u; ++j; }
    }
    reinterpret_cast<float4*>(R)[v] = make_float4(po[0], po[1], po[2], po[3]);
}

// ================= CSR build (by target) =================

// count in-degree: cnt[t]++
__global__ void hist_kernel(const int* __restrict__ tgt, int* __restrict__ cnt) {
    int e = blockIdx.x * 256 + threadIdx.x;
    if (e >= EE) return;
    atomicAdd(&cnt[tgt[e]], 1);
}

// single-block exclusive scan of 3072 counts -> rowptr[3073], cursor copy
__global__ __launch_bounds__(1024) void scan_kernel(const int* __restrict__ cnt,
                                                    int* __restrict__ rowptr,
                                                    int* __restrict__ cursor) {
    __shared__ int sums[1024];
    int tid = threadIdx.x;
    int base = tid * 3;
    int c0 = cnt[base], c1 = cnt[base + 1], c2 = cnt[base + 2];
    sums[tid] = c0 + c1 + c2;
    __syncthreads();
    for (int off = 1; off < 1024; off <<= 1) {
        int add = (tid >= off) ? sums[tid - off] : 0;
        __syncthreads();
        sums[tid] += add;
        __syncthreads();
    }
    int excl = (tid == 0) ? 0 : sums[tid - 1];
    rowptr[base] = excl;               cursor[base] = excl;
    rowptr[base + 1] = excl + c0;      cursor[base + 1] = excl + c0;
    rowptr[base + 2] = excl + c0 + c1; cursor[base + 2] = excl + c0 + c1;
    if (tid == 1023) rowptr[NN] = sums[1023];
}

// place each edge: srcs/eids arrays ordered by target
__global__ void scatter_kernel(const int* __restrict__ src, const int* __restrict__ tgt,
                               int* __restrict__ cursor,
                               int* __restrict__ srcs, int* __restrict__ eids) {
    int e = blockIdx.x * 256 + threadIdx.x;
    if (e >= EE) return;
    int t = tgt[e];
    int pos = atomicAdd(&cursor[t], 1);
    srcs[pos] = src[e];
    eids[pos] = e;
}

// ================= gather hops (no atomics) =================

// h1[t, k*3+d] = sum_e K[k,e] * x[src,d]
__global__ void hop1_kernel(const int* __restrict__ rowptr, const int* __restrict__ srcs,
                            const int* __restrict__ eids, const float* __restrict__ K,
                            const float* __restrict__ x, float* __restrict__ h1) {
    int id = blockIdx.x * 256 + threadIdx.x;
    if (id >= NN * 9) return;
    int t = id / 9;
    int c = id - t * 9;
    int k = c / 3, d = c - k * 3;
    int p0 = rowptr[t], p1 = rowptr[t + 1];
    const float* Kk = K + (size_t)k * EE;
    float acc = 0.0f;
    for (int p = p0; p < p1; ++p)
        acc += Kk[eids[p]] * x[srcs[p] * 3 + d];
    h1[id] = acc;
}

// h2[t, k*9+d] = sum_e K[k,e] * h1[src,d]
__global__ void hop2_kernel(const int* __restrict__ rowptr, const int* __restrict__ srcs,
                            const int* __restrict__ eids, const float* __restrict__ K,
                            const float* __restrict__ h1, float* __restrict__ h2) {
    int id = blockIdx.x * 256 + threadIdx.x;
    if (id >= NN * 27) return;
    int t = id / 27;
    int c = id - t * 27;
    int k = c / 9, d = c - k * 9;
    int p0 = rowptr[t], p1 = rowptr[t + 1];
    const float* Kk = K + (size_t)k * EE;
    float acc = 0.0f;
    for (int p = p0; p < p1; ++p)
        acc += Kk[eids[p]] * h1[srcs[p] * 9 + d];
    h2[id] = acc;
}

// agg numerator: agg[t, c] = sum_e [h1|h2][src, c]
__global__ void agg_kernel(const int* __restrict__ rowptr, const int* __restrict__ srcs,
                           const float* __restrict__ h1, const float* __restrict__ h2,
                           float* __restrict__ agg) {
    int id = blockIdx.x * 256 + threadIdx.x;
    if (id >= NN * CUMC) return;
    int t = id / CUMC;
    int c = id - t * CUMC;
    int p0 = rowptr[t], p1 = rowptr[t + 1];
    float acc = 0.0f;
    if (c < 9) {
        for (int p = p0; p < p1; ++p) acc += h1[srcs[p] * 9 + c];
    } else {
        int cc = c - 9;
        for (int p = p0; p < p1; ++p) acc += h2[srcs[p] * 27 + cc];
    }
    agg[id] = acc;
}

// ================= fused head: conv + mlp1 + mlp2, one block per node =======
__global__ __launch_bounds__(64) void head_kernel(const float* __restrict__ agg,
                                                  const int* __restrict__ rowptr,
                                                  const float* __restrict__ Wc,
                                                  const float* __restrict__ bc,
                                                  const float* __restrict__ W1,
                                                  const float* __restrict__ b1,
                                                  const float* __restrict__ W2,
                                                  const float* __restrict__ b2,
                                                  float* __restrict__ out) {
    int n = blockIdx.x;
    int tid = threadIdx.x;
    __shared__ float aL[CUMC];
    __shared__ float xL[CUMC];
    __shared__ float hL[HIDC];
    int dg = rowptr[n + 1] - rowptr[n];
    float inv = 1.0f / (float)(dg > 1 ? dg : 1);
    if (tid < CUMC) aL[tid] = agg[n * CUMC + tid] * inv;
    __syncthreads();
    if (tid < CUMC) {
        float acc = bc[tid];
#pragma unroll
        for (int k = 0; k < CUMC; ++k) acc += aL[k] * Wc[k * CUMC + tid];
        xL[tid] = acc > 0.0f ? acc : 0.0f;
    }
    __syncthreads();
    {
        float acc = b1[tid];
#pragma unroll
        for (int k = 0; k < CUMC; ++k) acc += xL[k] * W1[k * HIDC + tid];
        hL[tid] = acc > 0.0f ? acc : 0.0f;
    }
    __syncthreads();
    if (tid < OUTC) {
        float acc = b2[tid];
#pragma unroll
        for (int k = 0; k < HIDC; ++k) acc += hL[k] * W2[k * OUTC + tid];
        out[n * OUTC + tid] = acc;
    }
}

extern "C" void kernel_launch(void* const* d_in, const int* in_sizes, int n_in,
                              void* d_out, int out_size, void* d_ws, size_t ws_size,
                              hipStream_t stream) {
    const float* x   = (const float*)d_in[0];
    const int*   ei  = (const int*)  d_in[1];
    const float* Kv  = (const float*)d_in[2];
    const float* Ws  = (const float*)d_in[3];
    const float* bsh = (const float*)d_in[4];
    const float* Wc  = (const float*)d_in[5];
    const float* bc  = (const float*)d_in[6];
    const float* W1  = (const float*)d_in[7];
    const float* b1  = (const float*)d_in[8];
    const float* W2  = (const float*)d_in[9];
    const float* b2  = (const float*)d_in[10];

    const int* src = ei;
    const int* tgt = ei + EE;

    float* out  = (float*)d_out;                 // [N,5]
    float* Rout = out + NN * OUTC;               // [N,N,9], 16B-aligned

    // ---- workspace layout ----
    int* wsi = (int*)d_ws;
    int* cnt    = wsi;                 // 3072
    int* rowptr = cnt + NN;            // 3073
    int* cursor = rowptr + (NN + 1);   // 3072
    int* srcs   = cursor + NN;         // EE
    int* eids   = srcs + EE;           // EE
    float* wsf = (float*)(eids + EE);
    float* h1  = wsf;                  // N*9
    float* h2  = h1 + NN * 9;          // N*27
    float* agg = h2 + NN * 27;         // N*36
    float* Aa  = agg + NN * CUMC;      // N*9
    float* Bb  = Aa + NN * 9;          // N*9

    // zero only the histogram counters
    hipMemsetAsync(cnt, 0, NN * sizeof(int), stream);

    ab_kernel<<<(NN * 9 + 255) / 256, 256, 0, stream>>>(x, Ws, Aa, Bb);

    // big write-bound kernel: 84,934,656 floats / 4 per thread / 256 per block
    unsigned r_blocks = (unsigned)(((size_t)NN * NN * 9 / 4 + 255) / 256);  // 82944
    r_kernel<<<r_blocks, 256, 0, stream>>>(Aa, Bb, bsh, Rout);

    // CSR build
    hist_kernel<<<EE / 256, 256, 0, stream>>>(tgt, cnt);
    scan_kernel<<<1, 1024, 0, stream>>>(cnt, rowptr, cursor);
    scatter_kernel<<<EE / 256, 256, 0, stream>>>(src, tgt, cursor, srcs, eids);

    // gather hops
    hop1_kernel<<<(NN * 9 + 255) / 256, 256, 0, stream>>>(rowptr, srcs, eids, Kv, x, h1);
    hop2_kernel<<<(NN * 27 + 255) / 256, 256, 0, stream>>>(rowptr, srcs, eids, Kv, h1, h2);
    agg_kernel<<<(NN * CUMC + 255) / 256, 256, 0, stream>>>(rowptr, srcs, h1, h2, agg);

    // fused dense head
    head_kernel<<<NN, 64, 0, stream>>>(agg, rowptr, Wc, bc, W1, b1, W2, b2, out);
}